// Round 3
// baseline (5714.912 us; speedup 1.0000x reference)
//
#include <hip/hip_runtime.h>

// Problem constants
#define V_  32000
#define E_  256
#define H_  256
#define S_  128
#define B_  64
#define HID_ 30

// Accurate f32 activations
__device__ __forceinline__ float sigmoid_acc(float x) {
    return 1.0f / (1.0f + expf(-x));
}
__device__ __forceinline__ float tanh_acc(float x) {
    return tanhf(x);
}

// ---------------------------------------------------------------------------
// K1: f32 input-projection GEMM with fused embedding gather.
//   Xg[dir][m][g] = sum_k emb[concepts[m]][k] * Wih[g][k],  m = s*64+b
// ---------------------------------------------------------------------------
#define KC_ 64
#define LDP_ 68

__global__ __launch_bounds__(256) void gemm_f32_kernel(
    const int* __restrict__ concepts, const float* __restrict__ embedding,
    const float* __restrict__ Wih_f, const float* __restrict__ Wih_b,
    float* __restrict__ Xg) {
    __shared__ float Asub[KC_][LDP_];
    __shared__ float Bsub[KC_][LDP_];
    const int dir = blockIdx.y;
    const float* Wih = dir ? Wih_b : Wih_f;
    const int mt = blockIdx.x >> 4;
    const int nt = blockIdx.x & 15;
    const int m0 = mt * 64, n0 = nt * 64;
    const int t = threadIdx.x;
    const int lr = t >> 6;
    const int lk = t & 63;
    const int tm = (t & 15) * 4;
    const int tg = (t >> 4) * 4;

    float acc[4][4];
#pragma unroll
    for (int i = 0; i < 4; ++i)
#pragma unroll
        for (int j = 0; j < 4; ++j) acc[i][j] = 0.f;

    for (int kk = 0; kk < E_; kk += KC_) {
        __syncthreads();
#pragma unroll
        for (int p = 0; p < 16; ++p) {
            int r = 4 * p + lr;
            Asub[lk][r] = embedding[(size_t)concepts[m0 + r] * E_ + kk + lk];
            Bsub[lk][r] = Wih[(size_t)(n0 + r) * E_ + kk + lk];
        }
        __syncthreads();
#pragma unroll
        for (int k = 0; k < KC_; ++k) {
            float4 a = *(const float4*)&Asub[k][tm];
            float4 b = *(const float4*)&Bsub[k][tg];
            acc[0][0] = fmaf(a.x, b.x, acc[0][0]);
            acc[0][1] = fmaf(a.x, b.y, acc[0][1]);
            acc[0][2] = fmaf(a.x, b.z, acc[0][2]);
            acc[0][3] = fmaf(a.x, b.w, acc[0][3]);
            acc[1][0] = fmaf(a.y, b.x, acc[1][0]);
            acc[1][1] = fmaf(a.y, b.y, acc[1][1]);
            acc[1][2] = fmaf(a.y, b.z, acc[1][2]);
            acc[1][3] = fmaf(a.y, b.w, acc[1][3]);
            acc[2][0] = fmaf(a.z, b.x, acc[2][0]);
            acc[2][1] = fmaf(a.z, b.y, acc[2][1]);
            acc[2][2] = fmaf(a.z, b.z, acc[2][2]);
            acc[2][3] = fmaf(a.z, b.w, acc[2][3]);
            acc[3][0] = fmaf(a.w, b.x, acc[3][0]);
            acc[3][1] = fmaf(a.w, b.y, acc[3][1]);
            acc[3][2] = fmaf(a.w, b.z, acc[3][2]);
            acc[3][3] = fmaf(a.w, b.w, acc[3][3]);
        }
    }
    float* out = Xg + ((size_t)dir * 8192 + m0) * 1024 + n0;
#pragma unroll
    for (int i = 0; i < 4; ++i) {
        float4 v = make_float4(acc[i][0], acc[i][1], acc[i][2], acc[i][3]);
        *(float4*)&out[(size_t)(tm + i) * 1024 + tg] = v;
    }
}

// ---------------------------------------------------------------------------
// K2: LSTM, 4-way hidden-slice split. One dir per cooperative launch.
// Grid 256 = (b, q): WG owns units [64q, 64q+64) -> 256 gate rows.
// Thread t: row r=t>>2 (local; global row G = 256*(r>>6) + 64q + (r&63)),
// part p=t&3 owns 64 Whh elements in registers (rotated for bank-free LDS).
// Per step: dot -> shfl reduce -> act -> g_sh -> barrier ->
//   wave0 (t<64): c/h update, enc write, publish slice (fence+flag);
//   waves1-3 (64<=t<256): poll partner flags, pull 3 remote slices -> h_sh.
// Parity double-buffered publish slots make overwrite safe.
// ---------------------------------------------------------------------------
__global__ __launch_bounds__(1024, 4) void lstm4_kernel(
    const float* __restrict__ Xg,     // [8192][1024] (this dir)
    const float* __restrict__ Whh,    // [1024][256]
    const float* __restrict__ bias,   // [1024]
    const int* __restrict__ lens,
    float* __restrict__ enc,          // [B][S][512]
    float* __restrict__ Hpub,         // [B*4][2][64]
    unsigned int* __restrict__ flags, // [B*4]
    int dir) {
    const int wgid = blockIdx.x;      // 0..255
    const int b = wgid >> 2, q = wgid & 3;
    const int t = threadIdx.x;
    const int r = t >> 2, p = t & 3;
    const int gblk = r >> 6, jl = r & 63;
    const int G = (gblk << 8) + (q << 6) + jl;   // global gate row 0..1023
    const int len = lens[b];

    // Register-resident Whh slice: rows G, cols [64p, 64p+64), rotated by 2p
    float4 w4[16];
    const float4* wrow = (const float4*)(Whh + (size_t)G * H_ + (p << 6));
#pragma unroll
    for (int kk = 0; kk < 16; ++kk) w4[kk] = wrow[(kk + 2 * p) & 15];

    const float bias_r = bias[G];     // used by p==0 lane only

    __shared__ float h_sh[H_];        // full h (all 4 slices)
    __shared__ float g_sh[256];       // this WG's 256 gate activations
    if (t < H_) h_sh[t] = 0.f;
    float c = 0.f;                    // cell state for unit t (t<64)
    __syncthreads();

    // x prefetch (p==0 lanes)
    int srow0 = dir ? (len - 1) : 0;
    float xv = 0.f;
    if (p == 0) xv = Xg[(size_t)(srow0 * B_ + b) * 1024 + G];
    int srow = srow0;

    for (int s = 0; s < S_; ++s) {
        // prefetch next step's x
        float xv_next = 0.f;
        int srow_next = 0;
        if (s + 1 < S_) {
            int ns = s + 1;
            srow_next = dir ? ((ns < len) ? (len - 1 - ns) : ns) : ns;
            if (p == 0) xv_next = Xg[(size_t)(srow_next * B_ + b) * 1024 + G];
        }

        // partial dot: 64 elements, bank-conflict-free via 2p rotation
        const float4* h4 = (const float4*)h_sh;
        float4 a = {0.f, 0.f, 0.f, 0.f};
#pragma unroll
        for (int kk = 0; kk < 16; ++kk) {
            float4 hv = h4[(p << 4) + ((kk + 2 * p) & 15)];
            a.x = fmaf(w4[kk].x, hv.x, a.x);
            a.y = fmaf(w4[kk].y, hv.y, a.y);
            a.z = fmaf(w4[kk].z, hv.z, a.z);
            a.w = fmaf(w4[kk].w, hv.w, a.w);
        }
        float acc = (a.x + a.y) + (a.z + a.w);
        acc += __shfl_xor(acc, 1);
        acc += __shfl_xor(acc, 2);
        if (p == 0) {
            float gv = acc + bias_r + xv;
            // rows 128..191 (local) are the g-gate -> tanh; else sigmoid
            float act = (r >= 128 && r < 192) ? tanh_acc(gv) : sigmoid_acc(gv);
            g_sh[r] = act;
        }
        __syncthreads();   // A: g_sh complete; h_sh fully consumed

        if (t < 64) {
            float iv = g_sh[t], fv = g_sh[64 + t];
            float gg = g_sh[128 + t], ov = g_sh[192 + t];
            c = fv * c + iv * gg;
            float h = ov * tanh_acc(c);
            h_sh[(q << 6) + t] = h;
            int orow = dir ? srow : s;
            enc[((size_t)b * S_ + orow) * 512 + dir * H_ + (q << 6) + t] =
                (orow < len) ? h : 0.f;
            if (s + 1 < S_) {
                __hip_atomic_store(
                    &Hpub[((size_t)((b << 2) + q) * 2 + ((s + 1) & 1)) * 64 + t],
                    h, __ATOMIC_RELAXED, __HIP_MEMORY_SCOPE_AGENT);
                __threadfence();   // release: data before flag
                if (t == 0)
                    __hip_atomic_store(&flags[(b << 2) + q], (unsigned)(s + 1),
                                       __ATOMIC_RELEASE, __HIP_MEMORY_SCOPE_AGENT);
            }
        } else if (t < 256 && s + 1 < S_) {
            const int m = t >> 6;          // 1..3
            const int qq = (q + m) & 3;
            const int u = t & 63;
            const int idx = (b << 2) + qq;
            if (u == 0) {
                while (__hip_atomic_load(&flags[idx], __ATOMIC_RELAXED,
                                         __HIP_MEMORY_SCOPE_AGENT) < (unsigned)(s + 1)) {
                    __builtin_amdgcn_s_sleep(1);
                }
            }
            __threadfence();   // acquire: flag before data
            float hv = __hip_atomic_load(
                &Hpub[((size_t)idx * 2 + ((s + 1) & 1)) * 64 + u],
                __ATOMIC_RELAXED, __HIP_MEMORY_SCOPE_AGENT);
            h_sh[(qq << 6) + u] = hv;
        }
        if (s + 1 < S_) __syncthreads();   // B: h_sh ready for next step

        xv = xv_next;
        srow = srow_next;
    }
}

// ---------------------------------------------------------------------------
// K3: U = enc@Ua^T, W = enc@Wa^T
// ---------------------------------------------------------------------------
__global__ __launch_bounds__(256) void uw_kernel(
    const float* __restrict__ enc, const float* __restrict__ Ua,
    const float* __restrict__ Wa, float* __restrict__ U, float* __restrict__ Wout) {
    __shared__ float wgt[60][129];
    __shared__ float erow[4][128];
    const int tid = threadIdx.x;
    const int b = blockIdx.y, s0 = blockIdx.x * 32;
    const int rl = tid >> 6;
    const int d = tid & 63;
    const int dd = d & 31;
    const int isW = d >> 5;
    float acc[8];
#pragma unroll
    for (int i = 0; i < 8; ++i) acc[i] = 0.f;

    for (int kk = 0; kk < 4; ++kk) {
        __syncthreads();
        for (int i = tid; i < 30 * 128; i += 256) {
            int r = i >> 7, k = i & 127;
            wgt[r][k] = Ua[(size_t)r * 512 + kk * 128 + k];
            wgt[r + 30][k] = Wa[(size_t)r * 512 + kk * 128 + k];
        }
        for (int chunk = 0; chunk < 8; ++chunk) {
            __syncthreads();
            for (int i = tid; i < 4 * 128; i += 256) {
                int r = i >> 7, k = i & 127;
                erow[r][k] = enc[((size_t)b * S_ + (s0 + chunk * 4 + r)) * 512 + kk * 128 + k];
            }
            __syncthreads();
            if (dd < HID_) {
                const float* wr = wgt[dd + 30 * isW];
                const float* er = erow[rl];
                float a = acc[chunk];
#pragma unroll
                for (int k = 0; k < 128; ++k) a = fmaf(er[k], wr[k], a);
                acc[chunk] = a;
            }
        }
    }
    if (dd < HID_) {
        float* dst = isW ? Wout : U;
#pragma unroll
        for (int chunk = 0; chunk < 8; ++chunk)
            dst[((size_t)b * S_ + (s0 + chunk * 4 + rl)) * 32 + dd] = acc[chunk];
    }
}

// ---------------------------------------------------------------------------
// K4: scores + predictions
// ---------------------------------------------------------------------------
__global__ __launch_bounds__(256) void scores_kernel(
    const float* __restrict__ U, const float* __restrict__ W,
    const float* __restrict__ va,
    float* __restrict__ scores, float* __restrict__ preds) {
    __shared__ float w_sh[128][31];
    const int b = blockIdx.y, i0 = blockIdx.x * 32;
    const int tid = threadIdx.x;

    float va_r[HID_];
#pragma unroll
    for (int d2 = 0; d2 < HID_; ++d2) va_r[d2] = va[d2];

    for (int i = tid; i < 128 * HID_; i += 256) {
        int r = i / HID_, d2 = i - r * HID_;
        w_sh[r][d2] = W[((size_t)b * S_ + r) * 32 + d2];
    }
    __syncthreads();

    const int il = tid >> 3;
    const int jb = (tid & 7) * 16;
    float u_r[HID_];
    const float* urow = U + ((size_t)b * S_ + i0 + il) * 32;
#pragma unroll
    for (int d2 = 0; d2 < HID_; ++d2) u_r[d2] = urow[d2];

    const size_t obase = ((size_t)b * S_ + (i0 + il)) * S_;
    for (int jj = 0; jj < 16; ++jj) {
        int j = jb + jj;
        float acc = 0.f;
#pragma unroll
        for (int d2 = 0; d2 < HID_; ++d2)
            acc = fmaf(va_r[d2], tanh_acc(u_r[d2] + w_sh[j][d2]), acc);
        scores[obase + j] = acc;
        preds[obase + j] = (sigmoid_acc(acc) >= 0.5f) ? 1.f : 0.f;
    }
}

// ---------------------------------------------------------------------------
// Workspace layout (bytes):
//   Xg    @ 0          : 2*8192*1024*4 = 67,108,864
//   enc   @ 67,108,864 : 64*128*512*4  = 16,777,216
//   U     @ 83,886,080 : 8192*32*4     =  1,048,576
//   W     @ 84,934,656 : 8192*32*4     =  1,048,576
//   Hpub  @ 85,983,232 : 2*256*2*64*4  =   262,144
//   flags @ 86,245,376 : 2*256*4       =     2,048   (total ~86.25 MB)
// ---------------------------------------------------------------------------
extern "C" void kernel_launch(void* const* d_in, const int* in_sizes, int n_in,
                              void* d_out, int out_size, void* d_ws, size_t ws_size,
                              hipStream_t stream) {
    (void)in_sizes; (void)n_in; (void)out_size; (void)ws_size;
    const int* concepts = (const int*)d_in[0];
    const int* lens = (const int*)d_in[1];
    const float* embedding = (const float*)d_in[2];
    const float* Wih_f = (const float*)d_in[3];
    const float* Whh_f = (const float*)d_in[4];
    const float* b_f = (const float*)d_in[5];
    const float* Wih_b = (const float*)d_in[6];
    const float* Whh_b = (const float*)d_in[7];
    const float* b_b = (const float*)d_in[8];
    const float* Ua = (const float*)d_in[9];
    const float* Wa = (const float*)d_in[10];
    const float* va = (const float*)d_in[11];

    char* ws = (char*)d_ws;
    float* Xg = (float*)(ws + 0);
    float* enc = (float*)(ws + 67108864);
    float* U = (float*)(ws + 83886080);
    float* W = (float*)(ws + 84934656);
    float* Hpub = (float*)(ws + 85983232);
    unsigned int* flags = (unsigned int*)(ws + 86245376);

    float* scores = (float*)d_out;
    float* preds = scores + (size_t)B_ * S_ * S_;

    hipLaunchKernelGGL(gemm_f32_kernel, dim3(2048, 2), dim3(256), 0, stream,
                       concepts, embedding, Wih_f, Wih_b, Xg);

    // zero the handoff flags (ws is poisoned before every timed call)
    hipMemsetAsync(flags, 0, 2 * 256 * sizeof(unsigned int), stream);

    // forward then backward LSTM, each a cooperative launch (256 WGs = 1/CU)
    {
        const float* XgD = Xg;                    // dir 0
        float* HpubD = Hpub;
        unsigned int* flagsD = flags;
        int dir = 0;
        void* ka[] = {(void*)&XgD, (void*)&Whh_f, (void*)&b_f, (void*)&lens,
                      (void*)&enc, (void*)&HpubD, (void*)&flagsD, (void*)&dir};
        hipLaunchCooperativeKernel((const void*)lstm4_kernel, dim3(256), dim3(1024),
                                   ka, 0, stream);
    }
    {
        const float* XgD = Xg + (size_t)8192 * 1024;  // dir 1
        float* HpubD = Hpub + (size_t)256 * 2 * 64;
        unsigned int* flagsD = flags + 256;
        int dir = 1;
        void* ka[] = {(void*)&XgD, (void*)&Whh_b, (void*)&b_b, (void*)&lens,
                      (void*)&enc, (void*)&HpubD, (void*)&flagsD, (void*)&dir};
        hipLaunchCooperativeKernel((const void*)lstm4_kernel, dim3(256), dim3(1024),
                                   ka, 0, stream);
    }

    hipLaunchKernelGGL(uw_kernel, dim3(4, 64), dim3(256), 0, stream,
                       enc, Ua, Wa, U, W);
    hipLaunchKernelGGL(scores_kernel, dim3(4, 64), dim3(256), 0, stream,
                       U, W, va, scores, preds);
}

// Round 4
// 669.366 us; speedup vs baseline: 8.5378x; 8.5378x over previous
//
#include <hip/hip_runtime.h>

// Problem constants
#define V_  32000
#define E_  256
#define H_  256
#define S_  128
#define B_  64
#define HID_ 30

typedef float f32x2 __attribute__((ext_vector_type(2)));

// Accurate f32 activations
__device__ __forceinline__ float sigmoid_acc(float x) {
    return 1.0f / (1.0f + expf(-x));
}
__device__ __forceinline__ float tanh_acc(float x) {
    return tanhf(x);
}

// ---------------------------------------------------------------------------
// K0: build streamT: per (dir, side) the last 12 cols of each Whh row,
// transposed for coalesced per-step streaming.  sT[q][r], q = dir*6+side*3+j.
// ---------------------------------------------------------------------------
__global__ __launch_bounds__(256) void prep_stream_kernel(
    const float* __restrict__ Whh_f, const float* __restrict__ Whh_b,
    float4* __restrict__ sT) {
    int i = blockIdx.x * 256 + threadIdx.x;      // < 12*1024
    if (i >= 12 * 1024) return;
    int r = i & 1023;
    int q = i >> 10;                             // 0..11
    int j = q % 3;
    int side = (q % 6) / 3;
    int dir = q / 6;
    const float* Whh = dir ? Whh_b : Whh_f;
    const float* src = Whh + (size_t)r * H_ + side * 128 + 116 + 4 * j;
    sT[(size_t)q * 1024 + r] = make_float4(src[0], src[1], src[2], src[3]);
}

// ---------------------------------------------------------------------------
// K1: f32 input-projection GEMM with fused embedding gather.
//   Xg[dir][m][g] = sum_k emb[concepts[m]][k] * Wih[g][k],  m = s*64+b
// Inner product written as f32x2 pk-fma (bit-identical per-element fma).
// ---------------------------------------------------------------------------
#define KC_ 64
#define LDP_ 68

__global__ __launch_bounds__(256) void gemm_f32_kernel(
    const int* __restrict__ concepts, const float* __restrict__ embedding,
    const float* __restrict__ Wih_f, const float* __restrict__ Wih_b,
    float* __restrict__ Xg) {
    __shared__ float Asub[KC_][LDP_];
    __shared__ float Bsub[KC_][LDP_];
    const int dir = blockIdx.y;
    const float* Wih = dir ? Wih_b : Wih_f;
    const int mt = blockIdx.x >> 4;
    const int nt = blockIdx.x & 15;
    const int m0 = mt * 64, n0 = nt * 64;
    const int t = threadIdx.x;
    const int lr = t >> 6;
    const int lk = t & 63;
    const int tm = (t & 15) * 4;
    const int tg = (t >> 4) * 4;

    f32x2 acc2[4][2];
#pragma unroll
    for (int i = 0; i < 4; ++i) {
        acc2[i][0] = (f32x2){0.f, 0.f};
        acc2[i][1] = (f32x2){0.f, 0.f};
    }

    for (int kk = 0; kk < E_; kk += KC_) {
        __syncthreads();
#pragma unroll
        for (int p = 0; p < 16; ++p) {
            int r = 4 * p + lr;
            Asub[lk][r] = embedding[(size_t)concepts[m0 + r] * E_ + kk + lk];
            Bsub[lk][r] = Wih[(size_t)(n0 + r) * E_ + kk + lk];
        }
        __syncthreads();
#pragma unroll
        for (int k = 0; k < KC_; ++k) {
            float4 a = *(const float4*)&Asub[k][tm];
            float4 b = *(const float4*)&Bsub[k][tg];
            f32x2 b01 = (f32x2){b.x, b.y}, b23 = (f32x2){b.z, b.w};
            f32x2 ax = (f32x2){a.x, a.x}, ay = (f32x2){a.y, a.y};
            f32x2 az = (f32x2){a.z, a.z}, aw = (f32x2){a.w, a.w};
            acc2[0][0] = __builtin_elementwise_fma(ax, b01, acc2[0][0]);
            acc2[0][1] = __builtin_elementwise_fma(ax, b23, acc2[0][1]);
            acc2[1][0] = __builtin_elementwise_fma(ay, b01, acc2[1][0]);
            acc2[1][1] = __builtin_elementwise_fma(ay, b23, acc2[1][1]);
            acc2[2][0] = __builtin_elementwise_fma(az, b01, acc2[2][0]);
            acc2[2][1] = __builtin_elementwise_fma(az, b23, acc2[2][1]);
            acc2[3][0] = __builtin_elementwise_fma(aw, b01, acc2[3][0]);
            acc2[3][1] = __builtin_elementwise_fma(aw, b23, acc2[3][1]);
        }
    }
    float* out = Xg + ((size_t)dir * 8192 + m0) * 1024 + n0;
#pragma unroll
    for (int i = 0; i < 4; ++i) {
        float4 v = make_float4(acc2[i][0].x, acc2[i][0].y, acc2[i][1].x, acc2[i][1].y);
        *(float4*)&out[(size_t)(tm + i) * 1024 + tg] = v;
    }
}

// ---------------------------------------------------------------------------
// K2: LSTM, K-split pair design. 256 WGs x 512 thr, both dirs concurrent.
// wg: side = wg&1, pair P = wg>>1, dir = P&1, b = P>>1.
// WG(side) owns h-columns [128*side, 128*side+128) AND h-units of same range.
// Thread t: gate rows r0=t, r1=t+512, dot over its side's 128 cols:
//   40 col-pairs in registers (160 VGPR), 18 pairs in LDS (147 KB), 6 pairs
//   streamed coalesced from sT.  Partial sums for the partner's units are
//   handed off as packed (tag<<32 | f32) 64-bit relaxed agent atomics —
//   no fences, parity double-buffered slots.  h never crosses WGs.
// ---------------------------------------------------------------------------
#define RP 40
#define LP 18

__global__ __launch_bounds__(512, 2) void lstm_pair_kernel(
    const float* __restrict__ Xg,     // [2][8192][1024]
    const float* __restrict__ Whh_f, const float* __restrict__ Whh_b,
    const float* __restrict__ b_f, const float* __restrict__ b_b,
    const int* __restrict__ lens,
    float* __restrict__ enc,          // [B][S][512]
    unsigned long long* __restrict__ Xch,  // [128][2][1024]
    const float4* __restrict__ sT) {  // [12][1024]
    extern __shared__ f32x2 Wlds2[];  // [LP][1024]
    __shared__ f32x2 h_sh2[64];       // this side's 128 h values (local units)
    __shared__ float g_sh[2][128];    // f,o exchange between finalizer halves
    const int wg = blockIdx.x;
    const int side = wg & 1, P = wg >> 1;
    const int dir = P & 1, b = P >> 1;
    const int t = threadIdx.x;
    const int r0 = t, r1 = t + 512;
    const int u = t & 255;            // global unit of both rows
    const int ul = u & 127;
    const bool finalizer = ((u >> 7) == side);
    const int base = side << 7;
    const float* Whh = dir ? Whh_b : Whh_f;
    const float* bias = dir ? b_b : b_f;
    const int len = lens[b];

    // register-pinned pairs 0..RP-1 (cols base..base+79) of rows r0, r1
    f32x2 w0[RP], w1[RP];
    {
        const float4* p0 = (const float4*)(Whh + (size_t)r0 * H_ + base);
        const float4* p1 = (const float4*)(Whh + (size_t)r1 * H_ + base);
#pragma unroll
        for (int i = 0; i < RP / 2; ++i) {
            float4 v = p0[i];
            w0[2 * i] = (f32x2){v.x, v.y}; w0[2 * i + 1] = (f32x2){v.z, v.w};
            float4 q4 = p1[i];
            w1[2 * i] = (f32x2){q4.x, q4.y}; w1[2 * i + 1] = (f32x2){q4.z, q4.w};
        }
    }
    // LDS-pinned pairs RP..RP+LP-1 (cols base+80..base+115)
    for (int i = t; i < LP * 1024; i += 512) {
        int g = i >> 10, r = i & 1023;
        const float* src = Whh + (size_t)r * H_ + base + 80 + 2 * g;
        Wlds2[(size_t)g * 1024 + r] = (f32x2){src[0], src[1]};
    }
    const float bias0 = bias[r0], bias1 = bias[r1];
    const float4* sT0 = sT + (size_t)(dir * 6 + side * 3) * 1024;  // [j][r]
    unsigned long long* xch = Xch + (size_t)P * 2048;              // [par][1024]

    if (t < 64) h_sh2[t] = (f32x2){0.f, 0.f};
    float c = 0.f;                    // cell state (finalizer t<256 only)
    __syncthreads();

    // x prefetch (finalizers need rows r0, r1)
    int srow = dir ? (len - 1) : 0;   // len >= 1 guaranteed
    float x0 = 0.f, x1 = 0.f;
    if (finalizer) {
        const float* xp = Xg + (size_t)dir * 8192 * 1024 + (size_t)(srow * B_ + b) * 1024;
        x0 = xp[r0]; x1 = xp[r1];
    }

    for (int s = 0; s < S_; ++s) {
        // streamed weight pairs 58..63 (cols base+116..base+127), coalesced
        float4 s00 = sT0[r0], s01 = sT0[1024 + r0], s02 = sT0[2048 + r0];
        float4 s10 = sT0[r1], s11 = sT0[1024 + r1], s12 = sT0[2048 + r1];
        // next-step x prefetch
        int srow_n = 0; float x0n = 0.f, x1n = 0.f;
        if (s + 1 < S_) {
            int ns = s + 1;
            srow_n = dir ? ((ns < len) ? (len - 1 - ns) : ns) : ns;
            if (finalizer) {
                const float* xp = Xg + (size_t)dir * 8192 * 1024 +
                                  (size_t)(srow_n * B_ + b) * 1024;
                x0n = xp[r0]; x1n = xp[r1];
            }
        }

        f32x2 a0 = (f32x2){0.f, 0.f}, a1 = (f32x2){0.f, 0.f};
#pragma unroll
        for (int g = 0; g < RP; ++g) {
            f32x2 hv = h_sh2[g];                      // broadcast
            a0 = __builtin_elementwise_fma(w0[g], hv, a0);
            a1 = __builtin_elementwise_fma(w1[g], hv, a1);
        }
#pragma unroll
        for (int g = 0; g < LP; ++g) {
            f32x2 hv = h_sh2[RP + g];
            f32x2 wa = Wlds2[(size_t)g * 1024 + r0];
            f32x2 wb = Wlds2[(size_t)g * 1024 + r1];
            a0 = __builtin_elementwise_fma(wa, hv, a0);
            a1 = __builtin_elementwise_fma(wb, hv, a1);
        }
        {
            f32x2 h58 = h_sh2[58], h59 = h_sh2[59], h60 = h_sh2[60];
            f32x2 h61 = h_sh2[61], h62 = h_sh2[62], h63 = h_sh2[63];
            a0 = __builtin_elementwise_fma((f32x2){s00.x, s00.y}, h58, a0);
            a0 = __builtin_elementwise_fma((f32x2){s00.z, s00.w}, h59, a0);
            a0 = __builtin_elementwise_fma((f32x2){s01.x, s01.y}, h60, a0);
            a0 = __builtin_elementwise_fma((f32x2){s01.z, s01.w}, h61, a0);
            a0 = __builtin_elementwise_fma((f32x2){s02.x, s02.y}, h62, a0);
            a0 = __builtin_elementwise_fma((f32x2){s02.z, s02.w}, h63, a0);
            a1 = __builtin_elementwise_fma((f32x2){s10.x, s10.y}, h58, a1);
            a1 = __builtin_elementwise_fma((f32x2){s10.z, s10.w}, h59, a1);
            a1 = __builtin_elementwise_fma((f32x2){s11.x, s11.y}, h60, a1);
            a1 = __builtin_elementwise_fma((f32x2){s11.z, s11.w}, h61, a1);
            a1 = __builtin_elementwise_fma((f32x2){s12.x, s12.y}, h62, a1);
            a1 = __builtin_elementwise_fma((f32x2){s12.z, s12.w}, h63, a1);
        }
        float p0 = a0.x + a0.y, p1 = a1.x + a1.y;

        const unsigned tag = (unsigned)(s + 1);
        unsigned long long* slot = xch + (size_t)(s & 1) * 1024;
        float iv_s = 0.f, gv_s = 0.f;
        if (!finalizer) {
            // publish partials for the partner's rows (packed tag+data; no fence)
            __hip_atomic_store(&slot[r0],
                ((unsigned long long)tag << 32) | (unsigned long long)__float_as_uint(p0),
                __ATOMIC_RELAXED, __HIP_MEMORY_SCOPE_AGENT);
            __hip_atomic_store(&slot[r1],
                ((unsigned long long)tag << 32) | (unsigned long long)__float_as_uint(p1),
                __ATOMIC_RELAXED, __HIP_MEMORY_SCOPE_AGENT);
        } else {
            unsigned long long v;
            do {
                v = __hip_atomic_load(&slot[r0], __ATOMIC_RELAXED,
                                      __HIP_MEMORY_SCOPE_AGENT);
            } while ((unsigned)(v >> 32) != tag);
            p0 += __uint_as_float((unsigned)v) + bias0 + x0;
            do {
                v = __hip_atomic_load(&slot[r1], __ATOMIC_RELAXED,
                                      __HIP_MEMORY_SCOPE_AGENT);
            } while ((unsigned)(v >> 32) != tag);
            p1 += __uint_as_float((unsigned)v) + bias1 + x1;
            if (t < 256) {
                iv_s = sigmoid_acc(p0);         // i-gate
                gv_s = tanh_acc(p1);            // g-gate
            } else {
                g_sh[0][ul] = sigmoid_acc(p0);  // f-gate
                g_sh[1][ul] = sigmoid_acc(p1);  // o-gate
            }
        }
        __syncthreads();   // SYNC1: g_sh ready; all dots done (h_sh2 consumed)

        if (finalizer && t < 256) {
            float fv = g_sh[0][ul], ov = g_sh[1][ul];
            c = fv * c + iv_s * gv_s;
            float h = ov * tanh_acc(c);
            ((float*)h_sh2)[ul] = h;
            int orow = dir ? srow : s;
            enc[((size_t)b * S_ + orow) * 512 + dir * H_ + u] =
                (orow < len) ? h : 0.f;
        }
        __syncthreads();   // SYNC2: h_sh2 ready for next step

        srow = srow_n;
        x0 = x0n; x1 = x1n;
    }
}

// ---------------------------------------------------------------------------
// K3: U = enc@Ua^T, W = enc@Wa^T
// ---------------------------------------------------------------------------
__global__ __launch_bounds__(256) void uw_kernel(
    const float* __restrict__ enc, const float* __restrict__ Ua,
    const float* __restrict__ Wa, float* __restrict__ U, float* __restrict__ Wout) {
    __shared__ float wgt[60][129];
    __shared__ float erow[4][128];
    const int tid = threadIdx.x;
    const int b = blockIdx.y, s0 = blockIdx.x * 32;
    const int rl = tid >> 6;
    const int d = tid & 63;
    const int dd = d & 31;
    const int isW = d >> 5;
    float acc[8];
#pragma unroll
    for (int i = 0; i < 8; ++i) acc[i] = 0.f;

    for (int kk = 0; kk < 4; ++kk) {
        __syncthreads();
        for (int i = tid; i < 30 * 128; i += 256) {
            int r = i >> 7, k = i & 127;
            wgt[r][k] = Ua[(size_t)r * 512 + kk * 128 + k];
            wgt[r + 30][k] = Wa[(size_t)r * 512 + kk * 128 + k];
        }
        for (int chunk = 0; chunk < 8; ++chunk) {
            __syncthreads();
            for (int i = tid; i < 4 * 128; i += 256) {
                int r = i >> 7, k = i & 127;
                erow[r][k] = enc[((size_t)b * S_ + (s0 + chunk * 4 + r)) * 512 + kk * 128 + k];
            }
            __syncthreads();
            if (dd < HID_) {
                const float* wr = wgt[dd + 30 * isW];
                const float* er = erow[rl];
                float a = acc[chunk];
#pragma unroll
                for (int k = 0; k < 128; ++k) a = fmaf(er[k], wr[k], a);
                acc[chunk] = a;
            }
        }
    }
    if (dd < HID_) {
        float* dst = isW ? Wout : U;
#pragma unroll
        for (int chunk = 0; chunk < 8; ++chunk)
            dst[((size_t)b * S_ + (s0 + chunk * 4 + rl)) * 32 + dd] = acc[chunk];
    }
}

// ---------------------------------------------------------------------------
// K4: scores + predictions
// ---------------------------------------------------------------------------
__global__ __launch_bounds__(256) void scores_kernel(
    const float* __restrict__ U, const float* __restrict__ W,
    const float* __restrict__ va,
    float* __restrict__ scores, float* __restrict__ preds) {
    __shared__ float w_sh[128][31];
    const int b = blockIdx.y, i0 = blockIdx.x * 32;
    const int tid = threadIdx.x;

    float va_r[HID_];
#pragma unroll
    for (int d2 = 0; d2 < HID_; ++d2) va_r[d2] = va[d2];

    for (int i = tid; i < 128 * HID_; i += 256) {
        int r = i / HID_, d2 = i - r * HID_;
        w_sh[r][d2] = W[((size_t)b * S_ + r) * 32 + d2];
    }
    __syncthreads();

    const int il = tid >> 3;
    const int jb = (tid & 7) * 16;
    float u_r[HID_];
    const float* urow = U + ((size_t)b * S_ + i0 + il) * 32;
#pragma unroll
    for (int d2 = 0; d2 < HID_; ++d2) u_r[d2] = urow[d2];

    const size_t obase = ((size_t)b * S_ + (i0 + il)) * S_;
    for (int jj = 0; jj < 16; ++jj) {
        int j = jb + jj;
        float acc = 0.f;
#pragma unroll
        for (int d2 = 0; d2 < HID_; ++d2)
            acc = fmaf(va_r[d2], tanh_acc(u_r[d2] + w_sh[j][d2]), acc);
        scores[obase + j] = acc;
        preds[obase + j] = (sigmoid_acc(acc) >= 0.5f) ? 1.f : 0.f;
    }
}

// ---------------------------------------------------------------------------
// Workspace layout (bytes):
//   Xg   @ 0          : 2*8192*1024*4   = 67,108,864
//   enc  @ 67,108,864 : 64*128*512*4    = 16,777,216
//   U    @ 83,886,080 : 8192*32*4       =  1,048,576
//   W    @ 84,934,656 : 8192*32*4       =  1,048,576
//   Xch  @ 85,983,232 : 128*2*1024*8    =  2,097,152
//   sT   @ 88,080,384 : 12*1024*16      =    196,608   (total ~88.3 MB)
// ---------------------------------------------------------------------------
extern "C" void kernel_launch(void* const* d_in, const int* in_sizes, int n_in,
                              void* d_out, int out_size, void* d_ws, size_t ws_size,
                              hipStream_t stream) {
    (void)in_sizes; (void)n_in; (void)out_size; (void)ws_size;
    const int* concepts = (const int*)d_in[0];
    const int* lens = (const int*)d_in[1];
    const float* embedding = (const float*)d_in[2];
    const float* Wih_f = (const float*)d_in[3];
    const float* Whh_f = (const float*)d_in[4];
    const float* b_f = (const float*)d_in[5];
    const float* Wih_b = (const float*)d_in[6];
    const float* Whh_b = (const float*)d_in[7];
    const float* b_b = (const float*)d_in[8];
    const float* Ua = (const float*)d_in[9];
    const float* Wa = (const float*)d_in[10];
    const float* va = (const float*)d_in[11];

    char* ws = (char*)d_ws;
    float* Xg = (float*)(ws + 0);
    float* enc = (float*)(ws + 67108864);
    float* U = (float*)(ws + 83886080);
    float* W = (float*)(ws + 84934656);
    unsigned long long* Xch = (unsigned long long*)(ws + 85983232);
    float4* sT = (float4*)(ws + 88080384);

    float* scores = (float*)d_out;
    float* preds = scores + (size_t)B_ * S_ * S_;

    hipLaunchKernelGGL(prep_stream_kernel, dim3(48), dim3(256), 0, stream,
                       Whh_f, Whh_b, sT);
    hipLaunchKernelGGL(gemm_f32_kernel, dim3(2048, 2), dim3(256), 0, stream,
                       concepts, embedding, Wih_f, Wih_b, Xg);

    // zero handoff slots (ws is re-poisoned 0xAA before every timed call)
    hipMemsetAsync(Xch, 0, 2097152, stream);

    {
        const float* XgA = Xg;
        void* ka[] = {(void*)&XgA, (void*)&Whh_f, (void*)&Whh_b, (void*)&b_f,
                      (void*)&b_b, (void*)&lens, (void*)&enc, (void*)&Xch,
                      (void*)&sT};
        hipLaunchCooperativeKernel((const void*)lstm_pair_kernel, dim3(256),
                                   dim3(512), ka, LP * 1024 * sizeof(f32x2),
                                   stream);
    }

    hipLaunchKernelGGL(uw_kernel, dim3(4, 64), dim3(256), 0, stream,
                       enc, Ua, Wa, U, W);
    hipLaunchKernelGGL(scores_kernel, dim3(4, 64), dim3(256), 0, stream,
                       U, W, va, scores, preds);
}